// Round 1
// baseline (104.217 us; speedup 1.0000x reference)
//
#include <hip/hip_runtime.h>

constexpr int NN  = 64;
constexpr int STR = 68;   // padded stride (multiple of 4 for b128 alignment; 4-bank step)

// 64x64 fp32 tile-matmul helper: acc(4x4 tile at block ib,jb) = Asrc * Bsrc
__device__ __forceinline__ void mm64_tile(const float* Asrc, const float* Bsrc,
                                          int ib, int jb, float acc[4][4]) {
    #pragma unroll
    for (int ii = 0; ii < 4; ++ii)
        #pragma unroll
        for (int jj = 0; jj < 4; ++jj) acc[ii][jj] = 0.0f;
    #pragma unroll
    for (int n4 = 0; n4 < 16; ++n4) {
        float a[4][4], b[4][4];
        #pragma unroll
        for (int ii = 0; ii < 4; ++ii)
            *(float4*)a[ii] = *(const float4*)&Asrc[(4 * ib + ii) * STR + 4 * n4];
        #pragma unroll
        for (int c = 0; c < 4; ++c)
            *(float4*)b[c] = *(const float4*)&Bsrc[(4 * n4 + c) * STR + 4 * jb];
        #pragma unroll
        for (int ii = 0; ii < 4; ++ii)
            #pragma unroll
            for (int c = 0; c < 4; ++c)
                #pragma unroll
                for (int jj = 0; jj < 4; ++jj)
                    acc[ii][jj] = fmaf(a[ii][c], b[c][jj], acc[ii][jj]);
    }
}

__launch_bounds__(256)
__global__ void krylov_kernel(const float* __restrict__ A,
                              const float* __restrict__ Bv,
                              const float* __restrict__ Cv,
                              const float* __restrict__ logdt,
                              float* __restrict__ out)
{
    const int h    = blockIdx.x;
    const int tid  = threadIdx.x;
    const int ib   = tid >> 4;   // 0..15 row-block
    const int jb   = tid & 15;   // 0..15 col-block
    const int lane = tid & 63;
    const int wid  = tid >> 6;

    __shared__ __align__(16) float S1[NN * STR];   // dA, squaring ping, then E
    __shared__ __align__(16) float Vtt[NN * STR];  // Vtt[n][r] = v_r[n]
    __shared__ __align__(16) float S2[NN * STR];   // squaring pong, then Ut[q][n] = u_q[n]
    __shared__ __align__(16) float prow[2][NN];
    __shared__ __align__(16) float fcol[2][NN];
    __shared__ __align__(16) float vbuf[NN];
    __shared__ __align__(16) float ubuf[NN];
    __shared__ __align__(16) float Bl[NN];

    const float dt = expf(logdt[h]);
    const float cc = 0.5f * dt;

    if (tid < NN) Bl[tid] = Bv[h * NN + tid];

    // ---- build M = I - (dt/2)A into register 4x4 tiles ----
    float T[4][4];
    const float* Ah = A + (size_t)h * NN * NN;
    #pragma unroll
    for (int ii = 0; ii < 4; ++ii) {
        const int gi = 4 * ib + ii;
        float4 a4 = *(const float4*)(Ah + gi * NN + 4 * jb);
        T[ii][0] = (gi == 4 * jb + 0 ? 1.0f : 0.0f) - cc * a4.x;
        T[ii][1] = (gi == 4 * jb + 1 ? 1.0f : 0.0f) - cc * a4.y;
        T[ii][2] = (gi == 4 * jb + 2 ? 1.0f : 0.0f) - cc * a4.z;
        T[ii][3] = (gi == 4 * jb + 3 ? 1.0f : 0.0f) - cc * a4.w;
    }

    // ---- in-place Gauss-Jordan inversion, register tiles, 1 barrier/step ----
    for (int kb = 0; kb < 16; ++kb) {
        #pragma unroll
        for (int kk = 0; kk < 4; ++kk) {
            const int k  = 4 * kb + kk;
            const int pb = k & 1;
            if (ib == kb) {
                float4 pv = make_float4(T[kk][0], T[kk][1], T[kk][2], T[kk][3]);
                *(float4*)&prow[pb][4 * jb] = pv;
            }
            if (jb == kb) {
                fcol[pb][4 * ib + 0] = T[0][kk];
                fcol[pb][4 * ib + 1] = T[1][kk];
                fcol[pb][4 * ib + 2] = T[2][kk];
                fcol[pb][4 * ib + 3] = T[3][kk];
            }
            __syncthreads();
            float fc[4], pr[4];
            *(float4*)fc = *(const float4*)&fcol[pb][4 * ib];
            *(float4*)pr = *(const float4*)&prow[pb][4 * jb];
            const float p  = prow[pb][k];
            const float ip = 1.0f / p;
            float pj[4];
            #pragma unroll
            for (int jj = 0; jj < 4; ++jj) pj[jj] = pr[jj] * ip;
            const bool rb_ = (ib == kb), cb_ = (jb == kb);
            #pragma unroll
            for (int ii = 0; ii < 4; ++ii) {
                #pragma unroll
                for (int jj = 0; jj < 4; ++jj) {
                    const bool rowk = rb_ && (ii == kk);
                    const bool colk = cb_ && (jj == kk);
                    float g = T[ii][jj] - fc[ii] * pj[jj];
                    T[ii][jj] = rowk ? (colk ? ip : pj[jj])
                                     : (colk ? -fc[ii] * ip : g);
                }
            }
            // single barrier per step is safe: next write to this prow/fcol buffer
            // happens at step k+2, which is after the barrier of step k+1.
        }
    }
    // T = Inv = (I - dt/2 A)^-1

    // ---- dA = 2*Inv - I  -> S1 ----
    #pragma unroll
    for (int ii = 0; ii < 4; ++ii) {
        const int gi = 4 * ib + ii;
        float4 d4;
        d4.x = 2.0f * T[ii][0] - (gi == 4 * jb + 0 ? 1.0f : 0.0f);
        d4.y = 2.0f * T[ii][1] - (gi == 4 * jb + 1 ? 1.0f : 0.0f);
        d4.z = 2.0f * T[ii][2] - (gi == 4 * jb + 2 ? 1.0f : 0.0f);
        d4.w = 2.0f * T[ii][3] - (gi == 4 * jb + 3 ? 1.0f : 0.0f);
        *(float4*)&S1[gi * STR + 4 * jb] = d4;
    }
    __syncthreads();

    // ---- wave 0: preload dA row into regs; v0 = dB = (dt/2)(dA*B + B) ----
    float f[64];
    float v = 0.0f;
    if (wid == 0) {
        #pragma unroll
        for (int m = 0; m < 16; ++m) {
            float4 r4 = *(const float4*)&S1[lane * STR + 4 * m];
            f[4 * m + 0] = r4.x; f[4 * m + 1] = r4.y;
            f[4 * m + 2] = r4.z; f[4 * m + 3] = r4.w;
        }
        float acc = 0.0f;
        #pragma unroll
        for (int m = 0; m < 16; ++m) {
            float4 b4 = *(const float4*)&Bl[4 * m];
            acc += f[4*m+0]*b4.x + f[4*m+1]*b4.y + f[4*m+2]*b4.z + f[4*m+3]*b4.w;
        }
        v = cc * (acc + Bl[lane]);
        vbuf[lane] = v;
        Vtt[lane * STR + 0] = v;
    }
    __syncthreads();

    // ---- 6 squarings: E = dA^64, ping-pong S1 <-> S2, ends in S1 ----
    for (int s = 0; s < 6; ++s) {
        const float* src = (s & 1) ? S2 : S1;
        float*       dst = (s & 1) ? S1 : S2;
        float acc[4][4];
        mm64_tile(src, src, ib, jb, acc);
        #pragma unroll
        for (int ii = 0; ii < 4; ++ii)
            *(float4*)&dst[(4 * ib + ii) * STR + 4 * jb] = *(float4*)acc[ii];
        __syncthreads();
    }
    // E = dA^64 in S1

    // ---- concurrent chains: wave0: v_r = dA v_{r-1}; wave1: u_q = E^T u_{q-1} ----
    if (wid == 0) {
        for (int r = 1; r < 64; ++r) {
            float a0 = 0, a1 = 0, a2 = 0, a3 = 0;
            #pragma unroll
            for (int m = 0; m < 16; ++m) {
                float4 vb = *(const float4*)&vbuf[4 * m];
                a0 = fmaf(f[4*m+0], vb.x, a0);
                a1 = fmaf(f[4*m+1], vb.y, a1);
                a2 = fmaf(f[4*m+2], vb.z, a2);
                a3 = fmaf(f[4*m+3], vb.w, a3);
            }
            v = (a0 + a1) + (a2 + a3);
            __threadfence_block();   // reads of v_{r-1} complete before overwrite
            vbuf[lane] = v;
            Vtt[lane * STR + r] = v;
            __threadfence_block();   // vbuf write visible before next iter reads
        }
    } else if (wid == 1) {
        #pragma unroll
        for (int j = 0; j < 64; ++j) f[j] = S1[j * STR + lane];  // E^T row
        float u = Cv[h * NN + lane];
        ubuf[lane] = u;
        S2[0 * STR + lane] = u;
        __threadfence_block();
        for (int q = 1; q < 64; ++q) {
            float a0 = 0, a1 = 0, a2 = 0, a3 = 0;
            #pragma unroll
            for (int m = 0; m < 16; ++m) {
                float4 ub = *(const float4*)&ubuf[4 * m];
                a0 = fmaf(f[4*m+0], ub.x, a0);
                a1 = fmaf(f[4*m+1], ub.y, a1);
                a2 = fmaf(f[4*m+2], ub.z, a2);
                a3 = fmaf(f[4*m+3], ub.w, a3);
            }
            u = (a0 + a1) + (a2 + a3);
            __threadfence_block();
            ubuf[lane] = u;
            S2[q * STR + lane] = u;
            __threadfence_block();
        }
    }
    __syncthreads();

    // ---- final: Y[q][r] = sum_n Ut[q][n] * Vtt[n][r];  Ut == S2 ----
    float acc[4][4];
    mm64_tile(S2, Vtt, ib, jb, acc);
    float* oh = out + (size_t)h * 4096;
    #pragma unroll
    for (int ii = 0; ii < 4; ++ii) {
        *(float4*)(oh + (4 * ib + ii) * 64 + 4 * jb) = *(float4*)acc[ii];
    }
}

extern "C" void kernel_launch(void* const* d_in, const int* in_sizes, int n_in,
                              void* d_out, int out_size, void* d_ws, size_t ws_size,
                              hipStream_t stream) {
    const float* A  = (const float*)d_in[0];
    const float* B  = (const float*)d_in[1];
    const float* C  = (const float*)d_in[2];
    const float* ld = (const float*)d_in[3];
    float* out = (float*)d_out;
    const int H = in_sizes[3];   // 256 heads
    krylov_kernel<<<H, 256, 0, stream>>>(A, B, C, ld, out);
}